// Round 9
// baseline (103.513 us; speedup 1.0000x reference)
//
#include <hip/hip_runtime.h>
#include <hip/hip_bf16.h>

typedef short short8 __attribute__((ext_vector_type(8)));
typedef _Float16 half8 __attribute__((ext_vector_type(8)));
typedef __fp16 fp16x2 __attribute__((ext_vector_type(2)));
typedef float f32x4  __attribute__((ext_vector_type(4)));
typedef float f32x16 __attribute__((ext_vector_type(16)));

__device__ __forceinline__ unsigned short f2h(float f) {
  _Float16 h = (_Float16)f;   // v_cvt_f16_f32, RNE
  return __builtin_bit_cast(unsigned short, h);
}
__device__ __forceinline__ half8 as_h8(short8 s) { return __builtin_bit_cast(half8, s); }

// Fused QKV projection. C = A·B^T in fp16, written in MFMA-fragment-packed order.
// blockIdx.y selects {Q, K, V}. blockIdx.x is XCD-swizzled: batch = x&7 so each
// batch's packed tiles are produced (and stay) in that XCD's L2.
__global__ __launch_bounds__(256) void proj_kernel(
    const float* __restrict__ Aq, const float* __restrict__ Bq,
    const float* __restrict__ Ak, const float* __restrict__ Bk,
    const float* __restrict__ Av, const float* __restrict__ Bv,
    short* __restrict__ Cq, short* __restrict__ Ck, short* __restrict__ Cv) {
  __shared__ short At[128][40];
  __shared__ short Bt[128][40];
  const int y = blockIdx.y;
  const float* A  = (y == 0) ? Aq : (y == 1) ? Ak : Av;
  const float* Bm = (y == 0) ? Bq : (y == 1) ? Bk : Bv;
  short* C        = (y == 0) ? Cq : (y == 1) ? Ck : Cv;
  const int mode = (y == 2);
  const float scale = (y == 0) ? 1.44269504f : 1.0f;  // fold log2e into Q
  const int x = blockIdx.x;
  const int batch = x & 7, loc = (x >> 3) & 15, half = x >> 7;
  int m0, n0;
  if (!mode) { m0 = (batch * 16 + loc) * 128; n0 = half * 128; }
  else       { m0 = half * 128; n0 = (batch * 16 + loc) * 128; }

  const int t = threadIdx.x;
  const int w = t >> 6, l = t & 63;
  const int wr = (w >> 1) * 64, wc = (w & 1) * 64;
  f32x4 acc[4][4] = {};
  for (int k0 = 0; k0 < 256; k0 += 32) {
    __syncthreads();
    #pragma unroll
    for (int rep = 0; rep < 4; ++rep) {
      int row = (t >> 3) + rep * 32;
      int c4  = (t & 7) * 4;
      float4 va = *(const float4*)(A + (size_t)(m0 + row) * 256 + k0 + c4);
      unsigned long long pa = (unsigned long long)f2h(va.x) |
                              ((unsigned long long)f2h(va.y) << 16) |
                              ((unsigned long long)f2h(va.z) << 32) |
                              ((unsigned long long)f2h(va.w) << 48);
      *(unsigned long long*)&At[row][c4] = pa;
      float4 vb = *(const float4*)(Bm + (size_t)(n0 + row) * 256 + k0 + c4);
      unsigned long long pb = (unsigned long long)f2h(vb.x) |
                              ((unsigned long long)f2h(vb.y) << 16) |
                              ((unsigned long long)f2h(vb.z) << 32) |
                              ((unsigned long long)f2h(vb.w) << 48);
      *(unsigned long long*)&Bt[row][c4] = pb;
    }
    __syncthreads();
    short8 af[4], bf[4];
    #pragma unroll
    for (int i = 0; i < 4; ++i) {
      af[i] = *(const short8*)&At[wr + i * 16 + (l & 15)][(l >> 4) * 8];
      bf[i] = *(const short8*)&Bt[wc + i * 16 + (l & 15)][(l >> 4) * 8];
    }
    #pragma unroll
    for (int i = 0; i < 4; ++i)
      #pragma unroll
      for (int j = 0; j < 4; ++j)
        acc[i][j] = __builtin_amdgcn_mfma_f32_16x16x32_f16(as_h8(af[i]), as_h8(bf[j]),
                                                           acc[i][j], 0, 0, 0);
  }
  #pragma unroll
  for (int i = 0; i < 4; ++i)
    #pragma unroll
    for (int j = 0; j < 4; ++j)
      #pragma unroll
      for (int r = 0; r < 4; ++r) {
        int row = m0 + wr + i * 16 + (l >> 4) * 4 + r;
        int col = n0 + wc + j * 16 + (l & 15);
        size_t idx;
        if (!mode) {
          int b = row >> 11, s = row & 2047;
          int T = s >> 5, ln = s & 31;
          int kf = col >> 4, g = (col >> 3) & 1, jj = col & 7;
          idx = (((size_t)(b * 64 + T) * 16 + kf) * 64 + g * 32 + ln) * 8 + jj;
        } else {
          int b = col >> 11, s = col & 2047;
          int T = s >> 5, k2 = (s >> 4) & 1, g = (s >> 3) & 1, jj = s & 7;
          int db = row >> 5, ln = row & 31;
          idx = ((((size_t)(b * 64 + T) * 2 + k2) * 8 + db) * 64 + g * 32 + ln) * 8 + jj;
        }
        C[idx] = (short)f2h(acc[i][j][r] * scale);
      }
}

// Flash attention, 512-thread blocks (8 waves), 4 phases of 2 KV tiles/wave.
// 64 KV tiles = 4 phases x 2 tiles x 8 waves. Single-buffered P[16 slots].
// QK/softmax: wave w owns tiles ph*16+w and ph*16+8+w (slots w, w+8).
// Block-global running max via one LDS rendezvous per phase.
// PV: wave w owns d-slice [w*32,(w+1)*32), consumes all 16 P slots.
__global__ __launch_bounds__(512, 4) void attn_kernel(const short* __restrict__ QP,
                                                      const short* __restrict__ KP,
                                                      const short* __restrict__ VP,
                                                      float* __restrict__ O) {
  // arena: Qlds 16K | Plds 40K | mx 1K | lsh 1K ; tbuf(33K) overlays Qlds+Plds
  __shared__ __align__(16) char arena[16384 + 40960 + 1024 + 1024];
  short* Qlds = (short*)arena;
  short (*Plds)[32][40] = (short (*)[32][40])(arena + 16384);   // [16][32][40]
  float (*mx_sh)[8] = (float (*)[8])(arena + 16384 + 40960);
  float (*l_sh)[8]  = (float (*)[8])(arena + 16384 + 40960 + 1024);
  float (*tbuf)[32][33] = (float (*)[32][33])arena;   // epilogue only

  const int t = threadIdx.x;
  const int w = t >> 6, l = t & 63;
  const int q = l & 31, grp = l >> 5;
  const int bid = blockIdx.x;
  const int b = bid & 7;                  // XCD-local batch
  const int q0 = (bid >> 3) * 32;
  const size_t bS = (size_t)b * 2048;

  { // stage this q-tile's packed Q frags into LDS (shared by all 8 waves)
    const short* qsrc = QP + ((size_t)(b * 64 + (q0 >> 5)) * 16) * 512;
    *(short8*)&Qlds[t * 8] = *(const short8*)(qsrc + t * 8);
    *(short8*)&Qlds[(t + 512) * 8] = *(const short8*)(qsrc + (t + 512) * 8);
  }
  __syncthreads();

  const short* kptr = KP + (((size_t)(b * 64 + w)) << 13) + l * 8;
  const short* vptr = VP + (((size_t)(b * 64)) << 13) + ((size_t)w << 9) + l * 8;

  f32x16 ot0 = {}, ot1 = {};
  float m = -1e30f, lsum = 0.f;

  for (int ph = 0; ph < 4; ++ph) {
    // ---- QK tile A (slot w): T = ph*16 + w ----
    const short* kb0 = kptr + ((size_t)ph << 17);
    f32x16 s0a = {}, s1a = {};
    __builtin_amdgcn_s_setprio(1);
    #pragma unroll
    for (int kf = 0; kf < 16; kf += 2) {
      short8 a0 = *(const short8*)(kb0 + kf * 512);
      short8 a1 = *(const short8*)(kb0 + (kf + 1) * 512);
      short8 qa = *(const short8*)&Qlds[kf * 512 + l * 8];
      short8 qb = *(const short8*)&Qlds[(kf + 1) * 512 + l * 8];
      s0a = __builtin_amdgcn_mfma_f32_32x32x16_f16(as_h8(a0), as_h8(qa), s0a, 0, 0, 0);
      s1a = __builtin_amdgcn_mfma_f32_32x32x16_f16(as_h8(a1), as_h8(qb), s1a, 0, 0, 0);
    }
    f32x16 sta = s0a + s1a;
    // ---- QK tile B (slot w+8): T = ph*16 + 8 + w ----
    const short* kb1 = kb0 + 65536;
    f32x16 s0b = {}, s1b = {};
    #pragma unroll
    for (int kf = 0; kf < 16; kf += 2) {
      short8 a0 = *(const short8*)(kb1 + kf * 512);
      short8 a1 = *(const short8*)(kb1 + (kf + 1) * 512);
      short8 qa = *(const short8*)&Qlds[kf * 512 + l * 8];
      short8 qb = *(const short8*)&Qlds[(kf + 1) * 512 + l * 8];
      s0b = __builtin_amdgcn_mfma_f32_32x32x16_f16(as_h8(a0), as_h8(qa), s0b, 0, 0, 0);
      s1b = __builtin_amdgcn_mfma_f32_32x32x16_f16(as_h8(a1), as_h8(qb), s1b, 0, 0, 0);
    }
    __builtin_amdgcn_s_setprio(0);
    f32x16 stb = s0b + s1b;

    // ---- per-wave max over both tiles -> LDS -> block max ----
    float xa = fmaxf(fmaxf(fmaxf(sta[0], sta[1]), fmaxf(sta[2], sta[3])),
                     fmaxf(fmaxf(sta[4], sta[5]), fmaxf(sta[6], sta[7])));
    float xb = fmaxf(fmaxf(fmaxf(sta[8], sta[9]), fmaxf(sta[10], sta[11])),
                     fmaxf(fmaxf(sta[12], sta[13]), fmaxf(sta[14], sta[15])));
    float xc = fmaxf(fmaxf(fmaxf(stb[0], stb[1]), fmaxf(stb[2], stb[3])),
                     fmaxf(fmaxf(stb[4], stb[5]), fmaxf(stb[6], stb[7])));
    float xd = fmaxf(fmaxf(fmaxf(stb[8], stb[9]), fmaxf(stb[10], stb[11])),
                     fmaxf(fmaxf(stb[12], stb[13]), fmaxf(stb[14], stb[15])));
    float tmax = fmaxf(fmaxf(xa, xb), fmaxf(xc, xd));
    tmax = fmaxf(tmax, __shfl_xor(tmax, 32, 64));
    if (l < 32) mx_sh[q][w] = tmax;
    __syncthreads();   // A: mx visible; P buffer drained (prev PV done before this)

    f32x4 mA = *(const f32x4*)&mx_sh[q][0];
    f32x4 mB = *(const f32x4*)&mx_sh[q][4];
    float t8 = fmaxf(fmaxf(fmaxf(mA[0], mA[1]), fmaxf(mA[2], mA[3])),
                     fmaxf(fmaxf(mB[0], mB[1]), fmaxf(mB[2], mB[3])));

    // deferred rescale; condition identical in every wave (same t8, same m)
    if (!__all(t8 - m <= 11.544f)) {
      float mnew = fmaxf(m, t8);
      float corr = exp2f(m - mnew);
      lsum *= corr;
      ot0 *= corr;
      ot1 *= corr;
      m = mnew;
    }

    // ---- softmax + pack both tiles -> P slots w, w+8 ----
    float psum = 0.f;
    {
      float p[16];
      #pragma unroll
      for (int r = 0; r < 16; ++r) p[r] = exp2f(sta[r] - m);
      psum += ((p[0]+p[1])+(p[2]+p[3])) + ((p[4]+p[5])+(p[6]+p[7])) +
              ((p[8]+p[9])+(p[10]+p[11])) + ((p[12]+p[13])+(p[14]+p[15]));
      #pragma unroll
      for (int i = 0; i < 8; ++i) {
        fp16x2 pk = __builtin_amdgcn_cvt_pkrtz(p[2 * i], p[2 * i + 1]);
        int kvb = ((2 * i) & 3) + 8 * (i >> 1) + 4 * grp;
        *(unsigned*)&Plds[w][q][kvb] = __builtin_bit_cast(unsigned, pk);
      }
    }
    {
      float p[16];
      #pragma unroll
      for (int r = 0; r < 16; ++r) p[r] = exp2f(stb[r] - m);
      psum += ((p[0]+p[1])+(p[2]+p[3])) + ((p[4]+p[5])+(p[6]+p[7])) +
              ((p[8]+p[9])+(p[10]+p[11])) + ((p[12]+p[13])+(p[14]+p[15]));
      #pragma unroll
      for (int i = 0; i < 8; ++i) {
        fp16x2 pk = __builtin_amdgcn_cvt_pkrtz(p[2 * i], p[2 * i + 1]);
        int kvb = ((2 * i) & 3) + 8 * (i >> 1) + 4 * grp;
        *(unsigned*)&Plds[w + 8][q][kvb] = __builtin_bit_cast(unsigned, pk);
      }
    }
    psum += __shfl_xor(psum, 32, 64);
    lsum += psum;
    __syncthreads();   // B: all 16 P slots visible

    // ---- PV: wave's d-slice over 16 slots (slot s -> tile ph*16+s) ----
    const short* vb = vptr + ((size_t)ph << 17);
    __builtin_amdgcn_s_setprio(1);
    #pragma unroll
    for (int s = 0; s < 16; ++s) {
      short8 pb0 = *(const short8*)&Plds[s][q][grp * 8];
      short8 pb1 = *(const short8*)&Plds[s][q][16 + grp * 8];
      short8 vf0 = *(const short8*)(vb + s * 8192);
      short8 vf1 = *(const short8*)(vb + s * 8192 + 4096);
      ot0 = __builtin_amdgcn_mfma_f32_32x32x16_f16(as_h8(vf0), as_h8(pb0), ot0, 0, 0, 0);
      ot1 = __builtin_amdgcn_mfma_f32_32x32x16_f16(as_h8(vf1), as_h8(pb1), ot1, 0, 0, 0);
    }
    __builtin_amdgcn_s_setprio(0);
    // no trailing barrier: next phase's QK touches neither P nor mx; barrier A
    // of the next phase orders P reuse (every wave finished its PV before it).
  }

  // block lsum = sum of 8 per-wave partials (common m)
  if (l < 32) l_sh[q][w] = lsum;
  __syncthreads();
  f32x4 lA = *(const f32x4*)&l_sh[q][0];
  f32x4 lB = *(const f32x4*)&l_sh[q][4];
  float Ltot = ((lA[0] + lA[1]) + (lA[2] + lA[3])) + ((lB[0] + lB[1]) + (lB[2] + lB[3]));
  float invL = 1.0f / Ltot;
  __syncthreads();   // all l_sh reads done before tbuf overlays arena

  // scale, transpose via per-wave LDS buffer (overlaid arena), coalesced store
  #pragma unroll
  for (int r = 0; r < 16; ++r)
    tbuf[w][(r & 3) + 8 * (r >> 2) + 4 * grp][q] = (ot0[r] + ot1[r]) * invL;
  #pragma unroll
  for (int rr = 0; rr < 16; ++rr) {
    int qq = grp + rr * 2;
    O[(bS + q0 + qq) * 256 + w * 32 + q] = tbuf[w][q][qq];
  }
}

extern "C" void kernel_launch(void* const* d_in, const int* in_sizes, int n_in,
                              void* d_out, int out_size, void* d_ws, size_t ws_size,
                              hipStream_t stream) {
  (void)in_sizes; (void)n_in; (void)out_size; (void)ws_size;
  const float* query  = (const float*)d_in[0];
  const float* key_in = (const float*)d_in[1];
  const float* value  = (const float*)d_in[2];
  const float* Wq     = (const float*)d_in[3];
  const float* Wk     = (const float*)d_in[4];
  const float* Wv     = (const float*)d_in[5];
  float* out = (float*)d_out;

  short* q_ws = (short*)d_ws;                 // packed Q frags fp16 (pre-scaled by log2e), 8 MB
  short* k_ws = q_ws + (size_t)16384 * 256;   // packed K frags fp16, 8 MB
  short* v_ws = k_ws + (size_t)16384 * 256;   // packed V frags fp16, 8 MB

  dim3 gp(256, 3), ga(512);
  proj_kernel<<<gp, 256, 0, stream>>>(query, Wq, key_in, Wk, Wv, value,
                                      q_ws, k_ws, v_ws);
  attn_kernel<<<ga, 512, 0, stream>>>(q_ws, k_ws, v_ws, out);
}

// Round 10
// 82.183 us; speedup vs baseline: 1.2595x; 1.2595x over previous
//
#include <hip/hip_runtime.h>
#include <hip/hip_bf16.h>

typedef short short8 __attribute__((ext_vector_type(8)));
typedef _Float16 half8 __attribute__((ext_vector_type(8)));
typedef __fp16 fp16x2 __attribute__((ext_vector_type(2)));
typedef float f32x4  __attribute__((ext_vector_type(4)));
typedef float f32x16 __attribute__((ext_vector_type(16)));

__device__ __forceinline__ unsigned short f2h(float f) {
  _Float16 h = (_Float16)f;   // v_cvt_f16_f32, RNE
  return __builtin_bit_cast(unsigned short, h);
}
__device__ __forceinline__ half8 as_h8(short8 s) { return __builtin_bit_cast(half8, s); }

// Fused QKV projection. C = A·B^T in fp16, written in MFMA-fragment-packed order.
// blockIdx.y selects {Q, K, V}. blockIdx.x is XCD-swizzled: batch = x&7 so each
// batch's packed tiles are produced (and stay) in that XCD's L2.
__global__ __launch_bounds__(256) void proj_kernel(
    const float* __restrict__ Aq, const float* __restrict__ Bq,
    const float* __restrict__ Ak, const float* __restrict__ Bk,
    const float* __restrict__ Av, const float* __restrict__ Bv,
    short* __restrict__ Cq, short* __restrict__ Ck, short* __restrict__ Cv) {
  __shared__ short At[128][40];
  __shared__ short Bt[128][40];
  const int y = blockIdx.y;
  const float* A  = (y == 0) ? Aq : (y == 1) ? Ak : Av;
  const float* Bm = (y == 0) ? Bq : (y == 1) ? Bk : Bv;
  short* C        = (y == 0) ? Cq : (y == 1) ? Ck : Cv;
  const int mode = (y == 2);
  const float scale = (y == 0) ? 1.44269504f : 1.0f;  // fold log2e into Q
  const int x = blockIdx.x;
  const int batch = x & 7, loc = (x >> 3) & 15, half = x >> 7;
  int m0, n0;
  if (!mode) { m0 = (batch * 16 + loc) * 128; n0 = half * 128; }
  else       { m0 = half * 128; n0 = (batch * 16 + loc) * 128; }

  const int t = threadIdx.x;
  const int w = t >> 6, l = t & 63;
  const int wr = (w >> 1) * 64, wc = (w & 1) * 64;
  f32x4 acc[4][4] = {};
  for (int k0 = 0; k0 < 256; k0 += 32) {
    __syncthreads();
    #pragma unroll
    for (int rep = 0; rep < 4; ++rep) {
      int row = (t >> 3) + rep * 32;
      int c4  = (t & 7) * 4;
      float4 va = *(const float4*)(A + (size_t)(m0 + row) * 256 + k0 + c4);
      unsigned long long pa = (unsigned long long)f2h(va.x) |
                              ((unsigned long long)f2h(va.y) << 16) |
                              ((unsigned long long)f2h(va.z) << 32) |
                              ((unsigned long long)f2h(va.w) << 48);
      *(unsigned long long*)&At[row][c4] = pa;
      float4 vb = *(const float4*)(Bm + (size_t)(n0 + row) * 256 + k0 + c4);
      unsigned long long pb = (unsigned long long)f2h(vb.x) |
                              ((unsigned long long)f2h(vb.y) << 16) |
                              ((unsigned long long)f2h(vb.z) << 32) |
                              ((unsigned long long)f2h(vb.w) << 48);
      *(unsigned long long*)&Bt[row][c4] = pb;
    }
    __syncthreads();
    short8 af[4], bf[4];
    #pragma unroll
    for (int i = 0; i < 4; ++i) {
      af[i] = *(const short8*)&At[wr + i * 16 + (l & 15)][(l >> 4) * 8];
      bf[i] = *(const short8*)&Bt[wc + i * 16 + (l & 15)][(l >> 4) * 8];
    }
    #pragma unroll
    for (int i = 0; i < 4; ++i)
      #pragma unroll
      for (int j = 0; j < 4; ++j)
        acc[i][j] = __builtin_amdgcn_mfma_f32_16x16x32_f16(as_h8(af[i]), as_h8(bf[j]),
                                                           acc[i][j], 0, 0, 0);
  }
  #pragma unroll
  for (int i = 0; i < 4; ++i)
    #pragma unroll
    for (int j = 0; j < 4; ++j)
      #pragma unroll
      for (int r = 0; r < 4; ++r) {
        int row = m0 + wr + i * 16 + (l >> 4) * 4 + r;
        int col = n0 + wc + j * 16 + (l & 15);
        size_t idx;
        if (!mode) {
          int b = row >> 11, s = row & 2047;
          int T = s >> 5, ln = s & 31;
          int kf = col >> 4, g = (col >> 3) & 1, jj = col & 7;
          idx = (((size_t)(b * 64 + T) * 16 + kf) * 64 + g * 32 + ln) * 8 + jj;
        } else {
          int b = col >> 11, s = col & 2047;
          int T = s >> 5, k2 = (s >> 4) & 1, g = (s >> 3) & 1, jj = s & 7;
          int db = row >> 5, ln = row & 31;
          idx = ((((size_t)(b * 64 + T) * 2 + k2) * 8 + db) * 64 + g * 32 + ln) * 8 + jj;
        }
        C[idx] = (short)f2h(acc[i][j][r] * scale);
      }
}

// Flash attention, 512-thread blocks (8 waves). 64 KV tiles = 8 iters x 8 waves.
// QK/softmax: wave w owns KV tile it*8+w; block-global running max via LDS.
// PV: wave w owns d-slice [w*32,(w+1)*32), consumes all 8 P slots.
// K-frags 0-7 of the NEXT tile are prefetched into regs during softmax/PV (T14).
__global__ __launch_bounds__(512, 4) void attn_kernel(const short* __restrict__ QP,
                                                      const short* __restrict__ KP,
                                                      const short* __restrict__ VP,
                                                      float* __restrict__ O) {
  // arena: Qlds 16K | Plds 20K | mx 1K | lsh 1K = 38.9K; tbuf(33.8K) overlays Qlds+Plds
  __shared__ __align__(16) char arena[16384 + 20480 + 1024 + 1024];
  short* Qlds = (short*)arena;
  short (*Plds)[32][40] = (short (*)[32][40])(arena + 16384);   // [8][32][40]
  float (*mx_sh)[8] = (float (*)[8])(arena + 16384 + 20480);
  float (*l_sh)[8]  = (float (*)[8])(arena + 16384 + 20480 + 1024);
  float (*tbuf)[32][33] = (float (*)[32][33])arena;   // epilogue only

  const int t = threadIdx.x;
  const int w = t >> 6, l = t & 63;
  const int q = l & 31, grp = l >> 5;
  const int bid = blockIdx.x;
  const int b = bid & 7;                  // XCD-local batch
  const int q0 = (bid >> 3) * 32;
  const size_t bS = (size_t)b * 2048;

  const short* kptr = KP + (((size_t)(b * 64 + w)) << 13) + l * 8;
  const short* vptr = VP + (((size_t)(b * 64)) << 13) + ((size_t)w << 9) + l * 8;

  // prefetch K frags 0-7 of tile w (it=0) -- overlaps the Q staging below
  short8 ka[8];
  #pragma unroll
  for (int j = 0; j < 8; ++j) ka[j] = *(const short8*)(kptr + j * 512);

  { // stage this q-tile's packed Q frags into LDS (shared by all 8 waves)
    const short* qsrc = QP + ((size_t)(b * 64 + (q0 >> 5)) * 16) * 512;
    *(short8*)&Qlds[t * 8] = *(const short8*)(qsrc + t * 8);
    *(short8*)&Qlds[(t + 512) * 8] = *(const short8*)(qsrc + (t + 512) * 8);
  }
  __syncthreads();

  f32x16 ot0 = {}, ot1 = {};
  float m = -1e30f, lsum = 0.f;

  for (int it = 0; it < 8; ++it) {
    const short* kb = kptr + ((size_t)it << 16);
    // ---- QK(it): chain0 uses prefetched ka (frags 0-7), chain1 loads frags 8-15 ----
    f32x16 st0 = {}, st1 = {};
    __builtin_amdgcn_s_setprio(1);
    #pragma unroll
    for (int j = 0; j < 8; ++j) {
      short8 a1 = *(const short8*)(kb + (8 + j) * 512);
      short8 qa = *(const short8*)&Qlds[j * 512 + l * 8];
      short8 qb = *(const short8*)&Qlds[(8 + j) * 512 + l * 8];
      st0 = __builtin_amdgcn_mfma_f32_32x32x16_f16(as_h8(ka[j]), as_h8(qa), st0, 0, 0, 0);
      st1 = __builtin_amdgcn_mfma_f32_32x32x16_f16(as_h8(a1), as_h8(qb), st1, 0, 0, 0);
    }
    __builtin_amdgcn_s_setprio(0);
    // ---- prefetch K frags 0-7 of next tile (latency hides under softmax+PV) ----
    #pragma unroll
    for (int j = 0; j < 8; ++j) ka[j] = *(const short8*)(kb + 65536 + j * 512);

    f32x16 st = st0 + st1;

    float xa = fmaxf(fmaxf(fmaxf(st[0], st[1]), fmaxf(st[2], st[3])),
                     fmaxf(fmaxf(st[4], st[5]), fmaxf(st[6], st[7])));
    float xb = fmaxf(fmaxf(fmaxf(st[8], st[9]), fmaxf(st[10], st[11])),
                     fmaxf(fmaxf(st[12], st[13]), fmaxf(st[14], st[15])));
    float tmax = fmaxf(xa, xb);
    tmax = fmaxf(tmax, __shfl_xor(tmax, 32, 64));
    if (l < 32) mx_sh[q][w] = tmax;
    __syncthreads();   // A: mx visible; all P reads of prev iter complete

    f32x4 mA = *(const f32x4*)&mx_sh[q][0];
    f32x4 mB = *(const f32x4*)&mx_sh[q][4];
    float t8 = fmaxf(fmaxf(fmaxf(mA[0], mA[1]), fmaxf(mA[2], mA[3])),
                     fmaxf(fmaxf(mB[0], mB[1]), fmaxf(mB[2], mB[3])));

    // deferred rescale; condition identical in every wave (same t8, same m)
    if (!__all(t8 - m <= 11.544f)) {
      float mnew = fmaxf(m, t8);
      float corr = exp2f(m - mnew);
      lsum *= corr;
      ot0 *= corr;
      ot1 *= corr;
      m = mnew;
    }

    // ---- softmax in place over st ----
    #pragma unroll
    for (int r = 0; r < 16; ++r) st[r] = exp2f(st[r] - m);
    float s0 = (st[0] + st[1]) + (st[2] + st[3]);
    float s1 = (st[4] + st[5]) + (st[6] + st[7]);
    float s2 = (st[8] + st[9]) + (st[10] + st[11]);
    float s3 = (st[12] + st[13]) + (st[14] + st[15]);
    float psum = (s0 + s1) + (s2 + s3);
    psum += __shfl_xor(psum, 32, 64);
    lsum += psum;

    // pack P pairs -> LDS slot w
    #pragma unroll
    for (int i = 0; i < 8; ++i) {
      fp16x2 pk = __builtin_amdgcn_cvt_pkrtz(st[2 * i], st[2 * i + 1]);
      int kvb = ((2 * i) & 3) + 8 * (i >> 1) + 4 * grp;
      *(unsigned*)&Plds[w][q][kvb] = __builtin_bit_cast(unsigned, pk);
    }
    __syncthreads();   // B: all 8 P slots visible

    // ---- PV: wave's d-slice over all 8 slots (two chains: k2=0 -> ot0, k2=1 -> ot1) ----
    const short* vb = vptr + ((size_t)it << 16);
    __builtin_amdgcn_s_setprio(1);
    #pragma unroll
    for (int s = 0; s < 8; ++s) {
      short8 pb0 = *(const short8*)&Plds[s][q][grp * 8];
      short8 pb1 = *(const short8*)&Plds[s][q][16 + grp * 8];
      short8 vf0 = *(const short8*)(vb + s * 8192);
      short8 vf1 = *(const short8*)(vb + s * 8192 + 4096);
      ot0 = __builtin_amdgcn_mfma_f32_32x32x16_f16(as_h8(vf0), as_h8(pb0), ot0, 0, 0, 0);
      ot1 = __builtin_amdgcn_mfma_f32_32x32x16_f16(as_h8(vf1), as_h8(pb1), ot1, 0, 0, 0);
    }
    __builtin_amdgcn_s_setprio(0);
    // no trailing barrier: next iter's barrier A orders P-slot reuse.
  }

  // block lsum = sum of 8 per-wave partials (common m)
  if (l < 32) l_sh[q][w] = lsum;
  __syncthreads();
  f32x4 lA = *(const f32x4*)&l_sh[q][0];
  f32x4 lB = *(const f32x4*)&l_sh[q][4];
  float Ltot = ((lA[0] + lA[1]) + (lA[2] + lA[3])) + ((lB[0] + lB[1]) + (lB[2] + lB[3]));
  float invL = 1.0f / Ltot;

  // scale, transpose via per-wave LDS buffer (overlaid arena), coalesced store
  #pragma unroll
  for (int r = 0; r < 16; ++r)
    tbuf[w][(r & 3) + 8 * (r >> 2) + 4 * grp][q] = (ot0[r] + ot1[r]) * invL;
  #pragma unroll
  for (int rr = 0; rr < 16; ++rr) {
    int qq = grp + rr * 2;
    O[(bS + q0 + qq) * 256 + w * 32 + q] = tbuf[w][q][qq];
  }
}

extern "C" void kernel_launch(void* const* d_in, const int* in_sizes, int n_in,
                              void* d_out, int out_size, void* d_ws, size_t ws_size,
                              hipStream_t stream) {
  (void)in_sizes; (void)n_in; (void)out_size; (void)ws_size;
  const float* query  = (const float*)d_in[0];
  const float* key_in = (const float*)d_in[1];
  const float* value  = (const float*)d_in[2];
  const float* Wq     = (const float*)d_in[3];
  const float* Wk     = (const float*)d_in[4];
  const float* Wv     = (const float*)d_in[5];
  float* out = (float*)d_out;

  short* q_ws = (short*)d_ws;                 // packed Q frags fp16 (pre-scaled by log2e), 8 MB
  short* k_ws = q_ws + (size_t)16384 * 256;   // packed K frags fp16, 8 MB
  short* v_ws = k_ws + (size_t)16384 * 256;   // packed V frags fp16, 8 MB

  dim3 gp(256, 3), ga(512);
  proj_kernel<<<gp, 256, 0, stream>>>(query, Wq, key_in, Wk, Wv, value,
                                      q_ws, k_ws, v_ws);
  attn_kernel<<<ga, 512, 0, stream>>>(q_ws, k_ws, v_ws, out);
}